// Round 1
// baseline (213.348 us; speedup 1.0000x reference)
//
#include <hip/hip_runtime.h>

// Problem: out[b, x, y] = sum_k inputs[b,k] * W[y*82+x, k] + bias[y*82+x]
//   B=8192, F=64, P=5494 (NX=82, NY=67), out flat: b*5494 + x*67 + y = b*5494 + c
//   where c = x*67+y is the "permuted" column index, p(c) = (c%67)*82 + c/67.
//
// R4: single fused kernel (prep folded in — A/W read as f32, converted to bf16
// in-register, W permuted on the fly; no workspace, one launch) + XCD band
// swizzle. Theory: out row stride 21976 B (mod 128 = 88) makes every 128-col
// strip-row span 2 partial cachelines; neighboring strips previously landed on
// different XCDs (non-coherent L2s), so ~25% of written bytes evicted as
// partial lines -> write-allocate fetch + ECC RMW at HBM (gemm was ~2.2 TB/s
// effective vs 6.5 achievable). Remap: 2752 blocks = 8 XCDs x (8 bands x 43
// strips); all 43 strips of a band share one XCD and are co-resident
// (2 blocks/CU x 32 CU = 64 slots >= 43), so boundary lines merge in L2.

typedef __bf16 bf16x8 __attribute__((ext_vector_type(8)));
typedef unsigned short u16x8 __attribute__((ext_vector_type(8)));
typedef float f32x4 __attribute__((ext_vector_type(4)));
typedef float f32x4u __attribute__((ext_vector_type(4), aligned(4)));

#define B_DIM 8192
#define P_DIM 5494
#define NY_C 67

// round-to-nearest-even fp32 -> bf16 (matches prior verified kernel)
__device__ __forceinline__ unsigned short f2bf(float f) {
  unsigned int u = __float_as_uint(f);
  unsigned int r = u + 0x7fffu + ((u >> 16) & 1u);
  return (unsigned short)(r >> 16);
}

__device__ __forceinline__ bf16x8 cvt8(float4 v0, float4 v1) {
  u16x8 u;
  u[0] = f2bf(v0.x); u[1] = f2bf(v0.y); u[2] = f2bf(v0.z); u[3] = f2bf(v0.w);
  u[4] = f2bf(v1.x); u[5] = f2bf(v1.y); u[6] = f2bf(v1.z); u[7] = f2bf(v1.w);
  return __builtin_bit_cast(bf16x8, u);
}

// grid 2752 (1-D), 256 threads. 128x128 tile per block, 4 waves 2x2, 64x64/wave.
__global__ __launch_bounds__(256) void fused_gemm(
    const float* __restrict__ A,      // [8192, 64] f32
    const float* __restrict__ W,      // [5494, 64] f32 (unpermuted)
    const float* __restrict__ bias,   // [5494] f32
    float* __restrict__ out) {        // [8192, 5494] f32
  // --- XCD band swizzle: raw%8 ~ XCD (round-robin dispatch). Each XCD gets
  // 8 complete row bands of 43 strips, strips of a band consecutive in time.
  const int raw = blockIdx.x;          // 0..2751
  const int xcd = raw & 7;
  const int kk = raw >> 3;             // 0..343 (= 8 bands * 43 strips)
  const int band = kk / 43;            // 0..7 within this XCD
  const int xb = kk - band * 43;       // strip (col block) 0..42
  const int yb = xcd * 8 + band;       // row band 0..63

  const int tid = threadIdx.x;
  const int wid = tid >> 6;
  const int lane = tid & 63;
  const int quad = lane >> 4;
  const int l16 = lane & 15;
  const int wm = (wid >> 1) * 64;      // wave row offset in 128-tile
  const int wn = (wid & 1) * 64;       // wave col offset
  const int m0 = yb * 128 + wm;
  const int n0 = xb * 128 + wn;

  // Wave-private transpose buffers: [16 rows][68 cols] (+4-word pad -> <=2-way
  // bank conflicts both directions, 272 B row stride keeps 16 B alignment).
  __shared__ float lds[4][16][68];

  // A-op layout: lane holds A[m = l16][k = quad*8 + j], j=0..7
  // B-op layout: lane holds W[p(n = l16)][k = quad*8 + j]
  bf16x8 a_frag[4][2], b_frag[4][2];
  float biasv[4];
#pragma unroll
  for (int i = 0; i < 4; ++i) {
    const float* ar = A + (size_t)(m0 + i * 16 + l16) * 64 + quad * 8;
#pragma unroll
    for (int kb = 0; kb < 2; ++kb) {
      float4 v0 = *(const float4*)(ar + kb * 32);
      float4 v1 = *(const float4*)(ar + kb * 32 + 4);
      a_frag[i][kb] = cvt8(v0, v1);
    }
    // on-the-fly W permutation: col c -> W row p = (c%67)*82 + c/67
    int c = n0 + i * 16 + l16;
    int cc = c < P_DIM ? c : P_DIM - 1;  // clamp; cols >=5494 never stored
    int x = cc / NY_C;
    int y = cc - x * NY_C;
    int p = y * 82 + x;
    const float* wr = W + (size_t)p * 64 + quad * 8;
#pragma unroll
    for (int kb = 0; kb < 2; ++kb) {
      float4 v0 = *(const float4*)(wr + kb * 32);
      float4 v1 = *(const float4*)(wr + kb * 32 + 4);
      b_frag[i][kb] = cvt8(v0, v1);
    }
    biasv[i] = bias[p];  // valid (clamped); dead cols are store-guarded
  }

  f32x4 acc[4][4];
#pragma unroll
  for (int mi = 0; mi < 4; ++mi) {
#pragma unroll
    for (int ni = 0; ni < 4; ++ni) {
      f32x4 cacc = {0.0f, 0.0f, 0.0f, 0.0f};
      cacc = __builtin_amdgcn_mfma_f32_16x16x32_bf16(a_frag[mi][0], b_frag[ni][0], cacc, 0, 0, 0);
      cacc = __builtin_amdgcn_mfma_f32_16x16x32_bf16(a_frag[mi][1], b_frag[ni][1], cacc, 0, 0, 0);
      acc[mi][ni] = cacc;
    }
  }

  const bool fastn = (n0 + 63 < P_DIM);  // whole 64-col wave tile in-bounds
  // (wn==0 strips are always fast: 42*128+63 = 5439 < 5494)

  // Epilogue: per 16x64 acc slice (mi), stage to LDS in C/D layout
  // (row = quad*4+r, col = ni*16+l16), read back 4 consecutive cols per lane,
  // store dwordx4 (lanes 0-15 = 256 B contiguous per row-run).
#pragma unroll
  for (int mi = 0; mi < 4; ++mi) {
#pragma unroll
    for (int ni = 0; ni < 4; ++ni)
#pragma unroll
      for (int r = 0; r < 4; ++r)
        lds[wid][quad * 4 + r][ni * 16 + l16] = acc[mi][ni][r] + biasv[ni];
    // wave-private buffer: no __syncthreads needed; compiler inserts lgkmcnt
#pragma unroll
    for (int j = 0; j < 4; ++j) {
      const int row_l = 4 * j + (lane >> 4);
      const int c4 = 4 * (lane & 15);
      f32x4 v = *(const f32x4*)&lds[wid][row_l][c4];
      const int grow = m0 + mi * 16 + row_l;
      const int gcol = n0 + c4;
      float* p = out + (size_t)grow * P_DIM + gcol;
      if (fastn) {
        *(f32x4u*)p = v;
      } else {
#pragma unroll
        for (int e = 0; e < 4; ++e)
          if (gcol + e < P_DIM) p[e] = v[e];
      }
    }
  }
}

extern "C" void kernel_launch(void* const* d_in, const int* in_sizes, int n_in,
                              void* d_out, int out_size, void* d_ws, size_t ws_size,
                              hipStream_t stream) {
  (void)in_sizes; (void)n_in; (void)out_size; (void)d_ws; (void)ws_size;
  const float* A = (const float*)d_in[0];      // [8192, 64]
  const float* W = (const float*)d_in[1];      // [5494, 64]
  const float* bias = (const float*)d_in[2];   // [5494]
  float* out = (float*)d_out;                  // [8192, 82, 67, 1] contiguous

  fused_gemm<<<2752, 256, 0, stream>>>(A, W, bias, out);
}

// Round 2
// 206.525 us; speedup vs baseline: 1.0330x; 1.0330x over previous
//
#include <hip/hip_runtime.h>

// Problem: out[b, x, y] = sum_k inputs[b,k] * W[y*82+x, k] + bias[y*82+x]
//   B=8192, F=64, P=5494 (NX=82, NY=67); out flat: b*5494 + c, c = x*67+y,
//   inverse permutation p(c) = (c%67)*82 + c/67.
//
// R5: row-sequential writer. R3/R4's 128x128 tiling wrote each output row as
// 43 interleaved 512-B strips from different blocks (DRAM page misses +
// unmerged partial lines -> ~2.2 TB/s effective write BW). Now each block owns
// 16 FULL rows and sweeps all 5504 cols in 256-col chunks: per iteration one
// store instruction = 1024 B contiguous of one row, successive iterations
// extend the same rows -> page-sequential writes, partial lines merge in the
// same XCD's L2. A (block-private) is converted f32->bf16 in-kernel; W (shared
// by all 512 blocks) is prepped to permuted bf16 once. Double-buffered LDS
// transpose, 1 barrier/iter, b-fragments double-buffered (prefetch next chunk
// before MFMA of current).

typedef __bf16 bf16x8 __attribute__((ext_vector_type(8)));
typedef unsigned short u16x8 __attribute__((ext_vector_type(8)));
typedef float f32x4 __attribute__((ext_vector_type(4)));
typedef float f32x4u __attribute__((ext_vector_type(4), aligned(4)));

#define B_DIM 8192
#define P_DIM 5494
#define PP_DIM 5632   // P padded to 22*256
#define NY_C 67
#define NITER 22      // 5632 / 256 cols per block-iteration

// round-to-nearest-even fp32 -> bf16
__device__ __forceinline__ unsigned short f2bf(float f) {
  unsigned int u = __float_as_uint(f);
  unsigned int r = u + 0x7fffu + ((u >> 16) & 1u);
  return (unsigned short)(r >> 16);
}

__device__ __forceinline__ bf16x8 cvt8(float4 v0, float4 v1) {
  u16x8 u;
  u[0] = f2bf(v0.x); u[1] = f2bf(v0.y); u[2] = f2bf(v0.z); u[3] = f2bf(v0.w);
  u[4] = f2bf(v1.x); u[5] = f2bf(v1.y); u[6] = f2bf(v1.z); u[7] = f2bf(v1.w);
  return __builtin_bit_cast(bf16x8, u);
}

// Prep: permute+convert W rows to bf16 (Wp[c] = W[p(c)]), permuted zero-padded
// bias. 16 threads per row, 4 floats per thread. Grid 352 = 5632*16/256.
__global__ void prep_kernel(const float* __restrict__ W,
                            const float* __restrict__ bias,
                            unsigned short* __restrict__ Wp,
                            float* __restrict__ bp) {
  int t = blockIdx.x * 256 + threadIdx.x;
  int c = t >> 4;          // Wp row (permuted pixel index)
  int kq = (t & 15) * 4;   // k offset (4 floats)
  if (c < P_DIM) {
    int x = c / NY_C;
    int y = c - x * NY_C;
    int p = y * 82 + x;
    float4 v = *(const float4*)(W + p * 64 + kq);
    *(ushort4*)(Wp + c * 64 + kq) =
        make_ushort4(f2bf(v.x), f2bf(v.y), f2bf(v.z), f2bf(v.w));
    if (kq == 0) bp[c] = bias[p];
  } else {
    *(ushort4*)(Wp + c * 64 + kq) = make_ushort4(0, 0, 0, 0);
    if (kq == 0) bp[c] = 0.0f;
  }
}

// GEMM: grid 512 (1-D), 256 threads = 4 waves. Block owns rows m0..m0+15,
// sweeps 22 chunks of 256 cols (wave w -> cols chunk*256 + w*64 .. +64).
__global__ __launch_bounds__(256) void gemm_kernel(
    const float* __restrict__ A,            // [8192, 64] f32
    const unsigned short* __restrict__ Wp,  // [5632, 64] bf16 (permuted)
    const float* __restrict__ bp,           // [5632] f32 (permuted, padded)
    float* __restrict__ out) {              // [8192, 5494] f32
  const int tid = threadIdx.x;
  const int wid = tid >> 6;
  const int lane = tid & 63;
  const int quad = lane >> 4;
  const int l16 = lane & 15;
  const int m0 = blockIdx.x * 16;
  const int wn = wid * 64;   // wave col offset within 256-chunk

  // Double-buffered block-wide transpose: [buf][16 rows][256 cols + 4 pad].
  // Write phase: <=2-way bank aliasing (free). Read: contiguous b128.
  __shared__ float lds[2][16][260];

  // A fragments: lane holds A[m0+l16][k = quad*8 + j], converted in-register.
  // Block-private rows -> no cross-block redundancy in reading f32.
  const float* ar = A + (size_t)(m0 + l16) * 64 + quad * 8;
  bf16x8 a0 = cvt8(*(const float4*)(ar), *(const float4*)(ar + 4));
  bf16x8 a1 = cvt8(*(const float4*)(ar + 32), *(const float4*)(ar + 36));

  bf16x8 bA[4][2], bB[4][2];
  float biasA[4], biasB[4];

  auto loadB = [&](int it, bf16x8 (&bf)[4][2], float (&bv)[4]) {
    const int nb = it * 256 + wn;
#pragma unroll
    for (int ni = 0; ni < 4; ++ni) {
      const unsigned short* wr = Wp + (size_t)(nb + ni * 16 + l16) * 64 + quad * 8;
      bf[ni][0] = *(const bf16x8*)(wr);
      bf[ni][1] = *(const bf16x8*)(wr + 32);
      bv[ni] = bp[nb + ni * 16 + l16];
    }
  };

  // One chunk: prefetch next b-fragments, 8 MFMA, stage 16x256 to LDS with
  // bias, barrier, store 1024 B contiguous per row (4 rows per wave).
  auto body = [&](int it, bf16x8 (&bc)[4][2], float (&bvc)[4],
                  bf16x8 (&bn)[4][2], float (&bvn)[4], int buf) {
    if (it + 1 < NITER) loadB(it + 1, bn, bvn);
    f32x4 acc[4];
#pragma unroll
    for (int ni = 0; ni < 4; ++ni) {
      f32x4 c = {0.0f, 0.0f, 0.0f, 0.0f};
      c = __builtin_amdgcn_mfma_f32_16x16x32_bf16(a0, bc[ni][0], c, 0, 0, 0);
      c = __builtin_amdgcn_mfma_f32_16x16x32_bf16(a1, bc[ni][1], c, 0, 0, 0);
      acc[ni] = c;
    }
    // C/D layout: M row = quad*4+r, N col = ni*16+l16 (verified convention).
#pragma unroll
    for (int ni = 0; ni < 4; ++ni)
#pragma unroll
      for (int r = 0; r < 4; ++r)
        lds[buf][quad * 4 + r][wn + ni * 16 + l16] = acc[ni][r] + bvc[ni];
    __syncthreads();
    // Read complete before next write to same buf is guaranteed by the NEXT
    // body's barrier (reads' data consumed by stores before that barrier).
    const int nb = it * 256;
#pragma unroll
    for (int j = 0; j < 4; ++j) {
      const int row = wid * 4 + j;
      f32x4 v = *(const f32x4*)&lds[buf][row][lane * 4];
      const int gcol = nb + lane * 4;
      float* p = out + (size_t)(m0 + row) * P_DIM + gcol;
      if (it < NITER - 1) {
        *(f32x4u*)p = v;   // rows at stride 21976 B: 8-B misaligned half the
                           // time; HW handles dword-aligned dwordx4
      } else {
#pragma unroll
        for (int e = 0; e < 4; ++e)
          if (gcol + e < P_DIM) p[e] = v[e];
      }
    }
  };

  loadB(0, bA, biasA);
  for (int it = 0; it < NITER; it += 2) {
    body(it, bA, biasA, bB, biasB, 0);
    body(it + 1, bB, biasB, bA, biasA, 1);
  }
}

extern "C" void kernel_launch(void* const* d_in, const int* in_sizes, int n_in,
                              void* d_out, int out_size, void* d_ws, size_t ws_size,
                              hipStream_t stream) {
  (void)in_sizes; (void)n_in; (void)out_size; (void)ws_size;
  const float* A = (const float*)d_in[0];      // [8192, 64]
  const float* W = (const float*)d_in[1];      // [5494, 64]
  const float* bias = (const float*)d_in[2];   // [5494]
  float* out = (float*)d_out;                  // [8192, 82, 67, 1] contiguous

  // workspace: Wp 720896 B + bp 22528 B = ~0.74 MB
  unsigned short* Wp = (unsigned short*)d_ws;
  float* bp = (float*)((char*)d_ws + PP_DIM * 64 * sizeof(unsigned short));

  prep_kernel<<<PP_DIM * 16 / 256, 256, 0, stream>>>(W, bias, Wp, bp);
  gemm_kernel<<<B_DIM / 16, 256, 0, stream>>>(A, Wp, bp, out);
}